// Round 1
// 6516.973 us; speedup vs baseline: 1.1207x; 1.1207x over previous
//
#include <hip/hip_runtime.h>
#include <stdint.h>
#include <stddef.h>

#define TSEQ 512
#define NB   64
#define DI   1024
#define DHID 1024
#define NG   4096
#define NGRP 4     // independent batch groups (16 batch rows each)
#define WPG  64    // workgroups per group (16 hidden units each)
#define NWGS 256   // total persistent workgroups (1 per CU)
#define FPAD 32    // arrival-flag padding: 32 uints = 128 B (one LLC line per flag)

typedef __attribute__((ext_vector_type(8))) short short8;
typedef __attribute__((ext_vector_type(4))) float f32x4;

__device__ __forceinline__ unsigned short f2bf(float f) {
  union { float f; uint32_t u; } v; v.f = f;
  uint32_t u = v.u;
  uint32_t r = u + 0x7fffu + ((u >> 16) & 1u);
  return (unsigned short)(r >> 16);
}
__device__ __forceinline__ float bf2f(unsigned short b) {
  union { uint32_t u; float f; } v; v.u = ((uint32_t)b) << 16;
  return v.f;
}
__device__ __forceinline__ float fsigm(float x) { return 1.0f / (1.0f + __expf(-x)); }
__device__ __forceinline__ float ftanh(float x) { return 1.0f - 2.0f / (__expf(2.0f * x) + 1.0f); }

__device__ __forceinline__ void gll16(const void* g, void* l) {
  __builtin_amdgcn_global_load_lds(
      (const __attribute__((address_space(1))) void*)g,
      (__attribute__((address_space(3))) void*)l, 16, 0, 0);
}

// ---------------- K1: x fp32 -> bf16 ----------------
__global__ void k_convert_x(const float* __restrict__ x, unsigned short* __restrict__ xb, int n4) {
  int idx = blockIdx.x * blockDim.x + threadIdx.x;
  int stride = gridDim.x * blockDim.x;
  const float4* xf = (const float4*)x;
  for (int i = idx; i < n4; i += stride) {
    float4 v = xf[i];
    unsigned short o0 = f2bf(v.x), o1 = f2bf(v.y), o2 = f2bf(v.z), o3 = f2bf(v.w);
    uint2 packed;
    packed.x = (uint32_t)o0 | ((uint32_t)o1 << 16);
    packed.y = (uint32_t)o2 | ((uint32_t)o3 << 16);
    ((uint2*)xb)[i] = packed;
  }
}

// ---------------- K2: transpose W [1024][4096] fp32 -> [4096][1024] bf16 ----------------
__global__ void k_transpose_w(const float* __restrict__ w, unsigned short* __restrict__ wt) {
  __shared__ float tile[32][33];
  int n0 = blockIdx.x * 32;
  int k0 = blockIdx.y * 32;
  int c = threadIdx.x & 31, r0 = threadIdx.x >> 5;
  for (int r = r0; r < 32; r += 8)
    tile[r][c] = w[(size_t)(k0 + r) * NG + n0 + c];
  __syncthreads();
  for (int r = r0; r < 32; r += 8)
    wt[(size_t)(n0 + r) * 1024 + k0 + c] = f2bf(tile[c][r]);
}

// ---------------- K3: init (h0->bf16 blocked buf0, bsum, arrival slots) ----------------
// h ping-pong buffer layout is BLOCKED: [g][w][b][u] so each producer WG owns one
// contiguous 512B run (no cross-XCD 128B-line false sharing).
__global__ void k_init(const float* __restrict__ h0, const float* __restrict__ b_ih,
                       const float* __restrict__ b_hh, unsigned short* __restrict__ hbuf0,
                       float* __restrict__ bsum, unsigned* __restrict__ arrive) {
  int i = blockIdx.x * 256 + threadIdx.x;
  if (i < NB * DHID) {
    int bg = i >> 10, un = i & 1023;
    int gg = bg >> 4, bb = bg & 15, ww = un >> 4, uu = un & 15;
    hbuf0[((gg * WPG + ww) * 16 + bb) * 16 + uu] = f2bf(h0[i]);
  }
  if (i < NG) bsum[i] = b_ih[i] + b_hh[i];
  if (i < NGRP * WPG * FPAD) arrive[i] = 0u;
}

// ---------------- K4: pregate GEMM  pg = x_bf16 @ W_ih (permuted layout) ----------------
// Output permuted for k_lstm: idx = (((t*4+gb)*64+w)*1024) + bl*64 + gate*16 + u
template <bool PF32>
__global__ __launch_bounds__(256, 2) void k_gemm_pregates(
    const unsigned short* __restrict__ xb,
    const unsigned short* __restrict__ wt,
    void* __restrict__ pg) {
  __shared__ char lds_raw[32768];
  char* As = lds_raw;
  char* Bs = lds_raw + 16384;

  const int wave = threadIdx.x >> 6;
  const int lane = threadIdx.x & 63;
  const int ln = lane & 15, quad = lane >> 4;
  const int m0 = blockIdx.x * 128;
  const int n0 = blockIdx.y * 128;
  const int mw = (wave >> 1) * 64, nw = (wave & 1) * 64;

  f32x4 acc[4][4] = {};

  for (int kc = 0; kc < 16; ++kc) {
    __syncthreads();
#pragma unroll
    for (int i = 0; i < 4; ++i) {
      int s = wave * 256 + i * 64 + lane;
      int row = s >> 3;
      int kg = (s & 7) ^ (row & 7);
      gll16(xb + (size_t)(m0 + row) * 1024 + kc * 64 + kg * 8, As + s * 16);
      gll16(wt + (size_t)(n0 + row) * 1024 + kc * 64 + kg * 8, Bs + s * 16);
    }
    __syncthreads();

    short8 a[2][4], b[2][4];
#pragma unroll
    for (int kt = 0; kt < 2; ++kt) {
      int kg = kt * 4 + quad;
#pragma unroll
      for (int mt = 0; mt < 4; ++mt) {
        int row = mw + mt * 16 + ln;
        a[kt][mt] = *(const short8*)(As + (row * 8 + (kg ^ (row & 7))) * 16);
      }
#pragma unroll
      for (int nt = 0; nt < 4; ++nt) {
        int row = nw + nt * 16 + ln;
        b[kt][nt] = *(const short8*)(Bs + (row * 8 + (kg ^ (row & 7))) * 16);
      }
    }
#pragma unroll
    for (int kt = 0; kt < 2; ++kt)
#pragma unroll
      for (int mt = 0; mt < 4; ++mt)
#pragma unroll
        for (int nt = 0; nt < 4; ++nt)
          acc[mt][nt] = __builtin_amdgcn_mfma_f32_16x16x32_bf16(a[kt][mt], b[kt][nt], acc[mt][nt], 0, 0, 0);
  }

#pragma unroll
  for (int mt = 0; mt < 4; ++mt)
#pragma unroll
    for (int nt = 0; nt < 4; ++nt)
#pragma unroll
      for (int r = 0; r < 4; ++r) {
        int rowg = m0 + mw + mt * 16 + quad * 4 + r;
        int colg = n0 + nw + nt * 16 + ln;
        int t = rowg >> 6, bglob = rowg & 63;
        int gb = bglob >> 4, bl = bglob & 15;
        int gate = colg >> 10, j = colg & 1023;
        int w = j >> 4, u = j & 15;
        size_t idx = (((size_t)t * NGRP + gb) * WPG + w) * 1024 + (size_t)bl * 64 + gate * 16 + u;
        if (PF32)
          ((float*)pg)[idx] = acc[mt][nt][r];
        else
          ((unsigned short*)pg)[idx] = f2bf(acc[mt][nt][r]);
      }
}

// ---------------- K5: persistent recurrent kernel ----------------
// 256 WGs = 4 batch-groups (16 rows) x 64 WGs (16 hidden units).
// W_hh slice (128 KB) staged ONCE into LDS, layout [gate][kt][lane]*16B.
// K-SPLIT ACROSS WAVES: wave kq computes ALL 4 gates over kt in [kq*8, kq*8+8);
// partial sums exchanged via LDS (gl2) and reduced per-thread. This dedups the
// per-step h reload 4x (8 loads/lane, fully register-resident -> ONE LLC round
// trip) vs the old gate-split (32 loads/lane, VGPR-capped into serialized
// batches). Arrival flags padded to one 128B LLC line each (no hot-line
// serialization). h ping-pong buffer blocked [g][w][16][16].
template <bool PF32>
__global__ __launch_bounds__(256, 1) void k_lstm(
    const unsigned short* __restrict__ whhT,  // [4096][1024] bf16
    const void* __restrict__ pg,
    const float* __restrict__ c0,
    const float* __restrict__ bsum,
    unsigned short* __restrict__ hbuf,  // [2][NGRP][WPG][16][16] bf16
    float* __restrict__ out,            // [512][64][1024] ++ h_last ++ c_last
    unsigned* __restrict__ arrive) {    // [4][64][FPAD]
  const int bid = blockIdx.x;
  const int g = bid >> 6;   // batch group
  const int w = bid & 63;   // wg within group
  const int tid = threadIdx.x;
  const int wave = tid >> 6, lane = tid & 63;
  const int ln = lane & 15, quad = lane >> 4;

  __shared__ char wlds[4 * 32 * 1024];   // 128 KB: [gate][kt][lane]*16B
  __shared__ float gl2[4][4][16][17];    // [kq][gate][batch][unit], padded

  unsigned* arr = arrive + g * WPG * FPAD;

  // --- stage W_hh slice -> LDS (once). gll16: dst = wave-uniform + lane*16. ---
  {
    const unsigned short* src = whhT + (size_t)(wave * 1024 + w * 16 + ln) * 1024 + quad * 8;
    char* dst = wlds + wave * 32768;
#pragma unroll
    for (int kt = 0; kt < 32; ++kt)
      gll16(src + kt * 32, dst + kt * 1024);
  }
  __syncthreads();

  // --- per-thread activation state: one (batch,unit) element ---
  const int b = tid >> 4, u = tid & 15;
  const int bg = g * 16 + b;
  const int un = w * 16 + u;
  float cst = c0[(size_t)bg * DHID + un];
  const float bs0 = bsum[un], bs1 = bsum[1024 + un],
              bs2 = bsum[2048 + un], bs3 = bsum[3072 + un];

  const size_t out_hlast = (size_t)TSEQ * NB * DHID;
  const size_t out_clast = out_hlast + (size_t)NB * DHID;

  float p0, p1, p2, p3;
#define LDPG(T)                                                                      \
  {                                                                                  \
    size_t base = (((size_t)(T) * NGRP + g) * WPG + w) * 1024 + (size_t)b * 64 + u;  \
    if (PF32) {                                                                      \
      const float* pp = (const float*)pg;                                            \
      p0 = pp[base]; p1 = pp[base + 16]; p2 = pp[base + 32]; p3 = pp[base + 48];     \
    } else {                                                                         \
      const unsigned short* pp = (const unsigned short*)pg;                          \
      p0 = bf2f(pp[base]); p1 = bf2f(pp[base + 16]);                                 \
      p2 = bf2f(pp[base + 32]); p3 = bf2f(pp[base + 48]);                            \
    }                                                                                \
  }
  LDPG(0);

  for (int t = 0; t < TSEQ; ++t) {
    const unsigned short* hin = hbuf + (size_t)(t & 1) * (NB * DHID);
    unsigned short* hout = hbuf + (size_t)((t + 1) & 1) * (NB * DHID);
    const unsigned short* hg = hin + g * (WPG * 256);

    // ---- A-frags: this wave's K-quarter only (8 x 16B/lane, one LLC trip) ----
    short8 afr[8];
#pragma unroll
    for (int j = 0; j < 8; ++j) {
      int kt = wave * 8 + j;
      afr[j] = *(const short8*)(hg + kt * 512 + (quad >> 1) * 256 + ln * 16 + (quad & 1) * 8);
    }

    // ---- partial gates: all 4 gates over this wave's K-quarter ----
    f32x4 acc[4] = {};
#pragma unroll
    for (int gx = 0; gx < 4; ++gx) {
      const char* wbg = wlds + gx * 32768 + (wave * 8) * 1024 + lane * 16;
#pragma unroll
      for (int j = 0; j < 8; ++j) {
        short8 bfr = *(const short8*)(wbg + j * 1024);
        acc[gx] = __builtin_amdgcn_mfma_f32_16x16x32_bf16(afr[j], bfr, acc[gx], 0, 0, 0);
      }
    }
#pragma unroll
    for (int gx = 0; gx < 4; ++gx)
#pragma unroll
      for (int r = 0; r < 4; ++r)
        gl2[wave][gx][quad * 4 + r][ln] = acc[gx][r];
    __syncthreads();

    // ---- activation + state update (1 element/thread), reduce 4 K-partials ----
    float gi = ((gl2[0][0][b][u] + gl2[1][0][b][u]) + (gl2[2][0][b][u] + gl2[3][0][b][u])) + p0 + bs0;
    float gf = ((gl2[0][1][b][u] + gl2[1][1][b][u]) + (gl2[2][1][b][u] + gl2[3][1][b][u])) + p1 + bs1;
    float gg = ((gl2[0][2][b][u] + gl2[1][2][b][u]) + (gl2[2][2][b][u] + gl2[3][2][b][u])) + p2 + bs2;
    float go = ((gl2[0][3][b][u] + gl2[1][3][b][u]) + (gl2[2][3][b][u] + gl2[3][3][b][u])) + p3 + bs3;
    float i_ = fsigm(gi), f_ = fsigm(gf), g_ = ftanh(gg), o_ = fsigm(go);
    float cn = f_ * cst + i_ * g_;
    cst = cn;
    float h = o_ * ftanh(cn);
    out[((size_t)t * NB + bg) * DHID + un] = h;
    // blocked store: WG's 512B run is contiguous
    hout[g * (WPG * 256) + w * 256 + tid] = f2bf(h);
    if (t == TSEQ - 1) {
      out[out_hlast + (size_t)bg * DHID + un] = h;
      out[out_clast + (size_t)bg * DHID + un] = cn;
    }

    // ---- group barrier: ballot-style, no RMW, one LLC line per flag ----
    if (t < TSEQ - 1) {
      __syncthreads();  // drains hout stores (vmcnt 0) + protects gl2
      if (tid == 0)
        __hip_atomic_store(&arr[w * FPAD], (unsigned)(t + 1), __ATOMIC_RELEASE,
                           __HIP_MEMORY_SCOPE_AGENT);
      LDPG(t + 1);  // prefetch next pg; overlaps the spin below
      if (tid < 64) {
        const unsigned tgt = (unsigned)(t + 1);
        while (true) {
          unsigned v = __hip_atomic_load(&arr[tid * FPAD], __ATOMIC_RELAXED,
                                         __HIP_MEMORY_SCOPE_AGENT);
          if (__all((int)(v >= tgt))) break;
          __builtin_amdgcn_s_sleep(1);
        }
        __builtin_amdgcn_fence(__ATOMIC_ACQUIRE, "agent");
      }
      __syncthreads();
    }
  }
#undef LDPG
}

// ---------------- launcher ----------------
static inline size_t align_up(size_t x, size_t a) { return (x + a - 1) & ~(a - 1); }

extern "C" void kernel_launch(void* const* d_in, const int* in_sizes, int n_in,
                              void* d_out, int out_size, void* d_ws, size_t ws_size,
                              hipStream_t stream) {
  const float* x    = (const float*)d_in[0];
  const float* c0   = (const float*)d_in[1];
  const float* h0   = (const float*)d_in[2];
  const float* W_ih = (const float*)d_in[3];
  const float* W_hh = (const float*)d_in[4];
  const float* b_ih = (const float*)d_in[5];
  const float* b_hh = (const float*)d_in[6];
  float* out = (float*)d_out;

  const size_t pg_elems = (size_t)TSEQ * NB * NG;
  const size_t xb_bytes = (size_t)TSEQ * NB * DI * 2;
  const size_t wt_bytes = (size_t)NG * 1024 * 2;
  const size_t hb_bytes = (size_t)2 * NB * DHID * 2;
  const size_t bsum_bytes = (size_t)NG * 4;
  const size_t arr_bytes = (size_t)NGRP * WPG * FPAD * 4;

  auto layout = [&](size_t pg_bytes, size_t* offs) {
    size_t o = 0;
    offs[0] = o; o = align_up(o + pg_bytes, 256);
    offs[1] = o; o = align_up(o + xb_bytes, 256);
    offs[2] = o; o = align_up(o + wt_bytes, 256);
    offs[3] = o; o = align_up(o + wt_bytes, 256);
    offs[4] = o; o = align_up(o + hb_bytes, 256);
    offs[5] = o; o = align_up(o + bsum_bytes, 256);
    offs[6] = o; o = align_up(o + arr_bytes, 256);
    return o;
  };
  size_t offs[7];
  size_t need_f32 = layout(pg_elems * 4, offs);
  bool pf32 = ws_size >= need_f32;
  if (!pf32) layout(pg_elems * 2, offs);

  char* ws = (char*)d_ws;
  void* pg = ws + offs[0];
  unsigned short* xb   = (unsigned short*)(ws + offs[1]);
  unsigned short* wihT = (unsigned short*)(ws + offs[2]);
  unsigned short* whhT = (unsigned short*)(ws + offs[3]);
  unsigned short* hbuf = (unsigned short*)(ws + offs[4]);
  float* bsum = (float*)(ws + offs[5]);
  unsigned* arrive = (unsigned*)(ws + offs[6]);

  k_convert_x<<<2048, 256, 0, stream>>>(x, xb, (int)((size_t)TSEQ * NB * DI / 4));
  k_transpose_w<<<dim3(NG / 32, 1024 / 32), 256, 0, stream>>>(W_ih, wihT);
  k_transpose_w<<<dim3(NG / 32, 1024 / 32), 256, 0, stream>>>(W_hh, whhT);
  k_init<<<(NB * DHID + 255) / 256, 256, 0, stream>>>(h0, b_ih, b_hh, hbuf, bsum, arrive);

  dim3 ggrid(TSEQ * NB / 128, NG / 128);
  if (pf32)
    k_gemm_pregates<true><<<ggrid, 256, 0, stream>>>(xb, wihT, pg);
  else
    k_gemm_pregates<false><<<ggrid, 256, 0, stream>>>(xb, wihT, pg);

  if (pf32)
    k_lstm<true><<<NWGS, 256, 0, stream>>>(whhT, pg, c0, bsum, hbuf, out, arrive);
  else
    k_lstm<false><<<NWGS, 256, 0, stream>>>(whhT, pg, c0, bsum, hbuf, out, arrive);
}

// Round 2
// 2371.239 us; speedup vs baseline: 3.0801x; 2.7483x over previous
//
#include <hip/hip_runtime.h>
#include <stdint.h>
#include <stddef.h>

#define TSEQ 512
#define NB   64
#define DI   1024
#define DHID 1024
#define NG   4096
#define NGRP 4     // independent batch groups (16 batch rows each)
#define WPG  64    // workgroups per group (16 hidden units each)
#define NWGS 256   // total persistent workgroups (1 per CU)
#define FPAD 32    // arrival-flag padding: 32 uints = 128 B (one LLC line per flag)

typedef __attribute__((ext_vector_type(8))) short short8;
typedef __attribute__((ext_vector_type(4))) float f32x4;

__device__ __forceinline__ unsigned short f2bf(float f) {
  union { float f; uint32_t u; } v; v.f = f;
  uint32_t u = v.u;
  uint32_t r = u + 0x7fffu + ((u >> 16) & 1u);
  return (unsigned short)(r >> 16);
}
__device__ __forceinline__ float bf2f(unsigned short b) {
  union { uint32_t u; float f; } v; v.u = ((uint32_t)b) << 16;
  return v.f;
}
__device__ __forceinline__ float fsigm(float x) { return 1.0f / (1.0f + __expf(-x)); }
__device__ __forceinline__ float ftanh(float x) { return 1.0f - 2.0f / (__expf(2.0f * x) + 1.0f); }

__device__ __forceinline__ void gll16(const void* g, void* l) {
  __builtin_amdgcn_global_load_lds(
      (const __attribute__((address_space(1))) void*)g,
      (__attribute__((address_space(3))) void*)l, 16, 0, 0);
}

// ---- LLC-coherent (coherence-point) accesses: bypass non-coherent L2, no fences ----
__device__ __forceinline__ void st_dword_llc(void* addr, uint32_t val) {
  asm volatile("global_store_dword %0, %1, off sc0 sc1" :: "v"(addr), "v"(val) : "memory");
}
__device__ __forceinline__ short8 ld_b128_llc(const void* addr) {
  short8 v;
  asm volatile("global_load_dwordx4 %0, %1, off sc0 sc1" : "=v"(v) : "v"(addr) : "memory");
  return v;
}

// ---------------- K1: x fp32 -> bf16 ----------------
__global__ void k_convert_x(const float* __restrict__ x, unsigned short* __restrict__ xb, int n4) {
  int idx = blockIdx.x * blockDim.x + threadIdx.x;
  int stride = gridDim.x * blockDim.x;
  const float4* xf = (const float4*)x;
  for (int i = idx; i < n4; i += stride) {
    float4 v = xf[i];
    unsigned short o0 = f2bf(v.x), o1 = f2bf(v.y), o2 = f2bf(v.z), o3 = f2bf(v.w);
    uint2 packed;
    packed.x = (uint32_t)o0 | ((uint32_t)o1 << 16);
    packed.y = (uint32_t)o2 | ((uint32_t)o3 << 16);
    ((uint2*)xb)[i] = packed;
  }
}

// ---------------- K2: transpose W [1024][4096] fp32 -> [4096][1024] bf16 ----------------
__global__ void k_transpose_w(const float* __restrict__ w, unsigned short* __restrict__ wt) {
  __shared__ float tile[32][33];
  int n0 = blockIdx.x * 32;
  int k0 = blockIdx.y * 32;
  int c = threadIdx.x & 31, r0 = threadIdx.x >> 5;
  for (int r = r0; r < 32; r += 8)
    tile[r][c] = w[(size_t)(k0 + r) * NG + n0 + c];
  __syncthreads();
  for (int r = r0; r < 32; r += 8)
    wt[(size_t)(n0 + r) * 1024 + k0 + c] = f2bf(tile[c][r]);
}

// ---------------- K3: init (h0->bf16 blocked buf0, bsum, arrival slots) ----------------
// h ping-pong buffer layout is BLOCKED: [g][w][b][u] so each producer WG owns one
// contiguous 512B run (no cross-XCD 128B-line false sharing).
__global__ void k_init(const float* __restrict__ h0, const float* __restrict__ b_ih,
                       const float* __restrict__ b_hh, unsigned short* __restrict__ hbuf0,
                       float* __restrict__ bsum, unsigned* __restrict__ arrive) {
  int i = blockIdx.x * 256 + threadIdx.x;
  if (i < NB * DHID) {
    int bg = i >> 10, un = i & 1023;
    int gg = bg >> 4, bb = bg & 15, ww = un >> 4, uu = un & 15;
    hbuf0[((gg * WPG + ww) * 16 + bb) * 16 + uu] = f2bf(h0[i]);
  }
  if (i < NG) bsum[i] = b_ih[i] + b_hh[i];
  if (i < NGRP * WPG * FPAD) arrive[i] = 0u;
}

// ---------------- K4: pregate GEMM  pg = x_bf16 @ W_ih (permuted layout) ----------------
// Output permuted for k_lstm: idx = (((t*4+gb)*64+w)*1024) + bl*64 + gate*16 + u
template <bool PF32>
__global__ __launch_bounds__(256, 2) void k_gemm_pregates(
    const unsigned short* __restrict__ xb,
    const unsigned short* __restrict__ wt,
    void* __restrict__ pg) {
  __shared__ char lds_raw[32768];
  char* As = lds_raw;
  char* Bs = lds_raw + 16384;

  const int wave = threadIdx.x >> 6;
  const int lane = threadIdx.x & 63;
  const int ln = lane & 15, quad = lane >> 4;
  const int m0 = blockIdx.x * 128;
  const int n0 = blockIdx.y * 128;
  const int mw = (wave >> 1) * 64, nw = (wave & 1) * 64;

  f32x4 acc[4][4] = {};

  for (int kc = 0; kc < 16; ++kc) {
    __syncthreads();
#pragma unroll
    for (int i = 0; i < 4; ++i) {
      int s = wave * 256 + i * 64 + lane;
      int row = s >> 3;
      int kg = (s & 7) ^ (row & 7);
      gll16(xb + (size_t)(m0 + row) * 1024 + kc * 64 + kg * 8, As + s * 16);
      gll16(wt + (size_t)(n0 + row) * 1024 + kc * 64 + kg * 8, Bs + s * 16);
    }
    __syncthreads();

    short8 a[2][4], b[2][4];
#pragma unroll
    for (int kt = 0; kt < 2; ++kt) {
      int kg = kt * 4 + quad;
#pragma unroll
      for (int mt = 0; mt < 4; ++mt) {
        int row = mw + mt * 16 + ln;
        a[kt][mt] = *(const short8*)(As + (row * 8 + (kg ^ (row & 7))) * 16);
      }
#pragma unroll
      for (int nt = 0; nt < 4; ++nt) {
        int row = nw + nt * 16 + ln;
        b[kt][nt] = *(const short8*)(Bs + (row * 8 + (kg ^ (row & 7))) * 16);
      }
    }
#pragma unroll
    for (int kt = 0; kt < 2; ++kt)
#pragma unroll
      for (int mt = 0; mt < 4; ++mt)
#pragma unroll
        for (int nt = 0; nt < 4; ++nt)
          acc[mt][nt] = __builtin_amdgcn_mfma_f32_16x16x32_bf16(a[kt][mt], b[kt][nt], acc[mt][nt], 0, 0, 0);
  }

#pragma unroll
  for (int mt = 0; mt < 4; ++mt)
#pragma unroll
    for (int nt = 0; nt < 4; ++nt)
#pragma unroll
      for (int r = 0; r < 4; ++r) {
        int rowg = m0 + mw + mt * 16 + quad * 4 + r;
        int colg = n0 + nw + nt * 16 + ln;
        int t = rowg >> 6, bglob = rowg & 63;
        int gb = bglob >> 4, bl = bglob & 15;
        int gate = colg >> 10, j = colg & 1023;
        int w = j >> 4, u = j & 15;
        size_t idx = (((size_t)t * NGRP + gb) * WPG + w) * 1024 + (size_t)bl * 64 + gate * 16 + u;
        if (PF32)
          ((float*)pg)[idx] = acc[mt][nt][r];
        else
          ((unsigned short*)pg)[idx] = f2bf(acc[mt][nt][r]);
      }
}

// ---------------- K5: persistent recurrent kernel ----------------
// 256 WGs = 4 batch-groups (16 rows) x 64 WGs (16 hidden units).
// W_hh slice (128 KB) staged ONCE into LDS, layout [gate][kt][lane]*16B.
// K-split across waves (wave kq: all 4 gates over kt in [kq*8,kq*8+8)),
// partials exchanged via gl2.
// CROSS-WG PROTOCOL IS FENCE-FREE: h and flags move through the memory-side
// LLC with sc0 sc1 accesses (bypass the non-coherent per-XCD L2). No
// release/acquire fences -> NO buffer_wbl2 / buffer_inv in the loop (the old
// protocol issued 256 full-L2 writebacks + 256 full-L2 invalidates per step,
// synchronously flushing the freshly written `out` lines in the critical path).
// Ordering: h sc-stores -> s_waitcnt vmcnt(0) (per wave) -> __syncthreads ->
// flag sc-store; consumer: flag sc-load observed -> h sc-loads (LLC is the
// single coherence point, so data-at-flag implies data-at-load).
template <bool PF32>
__global__ __launch_bounds__(256, 1) void k_lstm(
    const unsigned short* __restrict__ whhT,  // [4096][1024] bf16
    const void* __restrict__ pg,
    const float* __restrict__ c0,
    const float* __restrict__ bsum,
    unsigned short* __restrict__ hbuf,  // [2][NGRP][WPG][16][16] bf16
    float* __restrict__ out,            // [512][64][1024] ++ h_last ++ c_last
    unsigned* __restrict__ arrive) {    // [4][64][FPAD]
  const int bid = blockIdx.x;
  const int g = bid >> 6;   // batch group
  const int w = bid & 63;   // wg within group
  const int tid = threadIdx.x;
  const int wave = tid >> 6, lane = tid & 63;
  const int ln = lane & 15, quad = lane >> 4;

  __shared__ char wlds[4 * 32 * 1024];   // 128 KB: [gate][kt][lane]*16B
  __shared__ float gl2[4][4][16][17];    // [kq][gate][batch][unit], padded

  unsigned* arr = arrive + g * WPG * FPAD;

  // --- stage W_hh slice -> LDS (once). gll16: dst = wave-uniform + lane*16. ---
  {
    const unsigned short* src = whhT + (size_t)(wave * 1024 + w * 16 + ln) * 1024 + quad * 8;
    char* dst = wlds + wave * 32768;
#pragma unroll
    for (int kt = 0; kt < 32; ++kt)
      gll16(src + kt * 32, dst + kt * 1024);
  }
  __syncthreads();

  // --- per-thread activation state: one (batch,unit) element ---
  const int b = tid >> 4, u = tid & 15;
  const int bg = g * 16 + b;
  const int un = w * 16 + u;
  float cst = c0[(size_t)bg * DHID + un];
  const float bs0 = bsum[un], bs1 = bsum[1024 + un],
              bs2 = bsum[2048 + un], bs3 = bsum[3072 + un];

  const size_t out_hlast = (size_t)TSEQ * NB * DHID;
  const size_t out_clast = out_hlast + (size_t)NB * DHID;

  float p0, p1, p2, p3;
#define LDPG(T)                                                                      \
  {                                                                                  \
    size_t base = (((size_t)(T) * NGRP + g) * WPG + w) * 1024 + (size_t)b * 64 + u;  \
    if (PF32) {                                                                      \
      const float* pp = (const float*)pg;                                            \
      p0 = pp[base]; p1 = pp[base + 16]; p2 = pp[base + 32]; p3 = pp[base + 48];     \
    } else {                                                                         \
      const unsigned short* pp = (const unsigned short*)pg;                          \
      p0 = bf2f(pp[base]); p1 = bf2f(pp[base + 16]);                                 \
      p2 = bf2f(pp[base + 32]); p3 = bf2f(pp[base + 48]);                            \
    }                                                                                \
  }
  LDPG(0);

  for (int t = 0; t < TSEQ; ++t) {
    const unsigned short* hin = hbuf + (size_t)(t & 1) * (NB * DHID);
    unsigned short* hout = hbuf + (size_t)((t + 1) & 1) * (NB * DHID);
    const unsigned short* hg = hin + g * (WPG * 256);

    // ---- A-frags: this wave's K-quarter, LLC-coherent loads (bypass L2) ----
    short8 afr[8];
#pragma unroll
    for (int j = 0; j < 8; ++j) {
      int kt = wave * 8 + j;
      afr[j] = ld_b128_llc(hg + kt * 512 + (quad >> 1) * 256 + ln * 16 + (quad & 1) * 8);
    }
    asm volatile("s_waitcnt vmcnt(0)" ::: "memory");
    __builtin_amdgcn_sched_barrier(0);

    // ---- partial gates: all 4 gates over this wave's K-quarter ----
    f32x4 acc[4] = {};
#pragma unroll
    for (int gx = 0; gx < 4; ++gx) {
      const char* wbg = wlds + gx * 32768 + (wave * 8) * 1024 + lane * 16;
#pragma unroll
      for (int j = 0; j < 8; ++j) {
        short8 bfr = *(const short8*)(wbg + j * 1024);
        acc[gx] = __builtin_amdgcn_mfma_f32_16x16x32_bf16(afr[j], bfr, acc[gx], 0, 0, 0);
      }
    }
#pragma unroll
    for (int gx = 0; gx < 4; ++gx)
#pragma unroll
      for (int r = 0; r < 4; ++r)
        gl2[wave][gx][quad * 4 + r][ln] = acc[gx][r];
    __syncthreads();

    // ---- activation + state update (1 element/thread), reduce 4 K-partials ----
    float gi = ((gl2[0][0][b][u] + gl2[1][0][b][u]) + (gl2[2][0][b][u] + gl2[3][0][b][u])) + p0 + bs0;
    float gf = ((gl2[0][1][b][u] + gl2[1][1][b][u]) + (gl2[2][1][b][u] + gl2[3][1][b][u])) + p1 + bs1;
    float gg = ((gl2[0][2][b][u] + gl2[1][2][b][u]) + (gl2[2][2][b][u] + gl2[3][2][b][u])) + p2 + bs2;
    float go = ((gl2[0][3][b][u] + gl2[1][3][b][u]) + (gl2[2][3][b][u] + gl2[3][3][b][u])) + p3 + bs3;
    float i_ = fsigm(gi), f_ = fsigm(gf), g_ = ftanh(gg), o_ = fsigm(go);
    float cn = f_ * cst + i_ * g_;
    cst = cn;
    float h = o_ * ftanh(cn);
    out[((size_t)t * NB + bg) * DHID + un] = h;

    // blocked h store: pack 2 bf16/dword, sc0 sc1 -> LLC (no L2 dirty lines)
    float hn = __shfl_xor(h, 1);
    if (!(tid & 1)) {
      uint32_t pk = (uint32_t)f2bf(h) | ((uint32_t)f2bf(hn) << 16);
      st_dword_llc((void*)(hout + g * (WPG * 256) + w * 256 + tid), pk);
    }

    if (t == TSEQ - 1) {
      out[out_hlast + (size_t)bg * DHID + un] = h;
      out[out_clast + (size_t)bg * DHID + un] = cn;
    }

    // ---- group barrier: fence-free ballot via LLC flags ----
    if (t < TSEQ - 1) {
      asm volatile("s_waitcnt vmcnt(0)" ::: "memory");  // h stores at coherence point
      __syncthreads();                                  // all 4 waves drained + gl2 safe
      if (tid == 0)
        __hip_atomic_store(&arr[w * FPAD], (unsigned)(t + 1), __ATOMIC_RELAXED,
                           __HIP_MEMORY_SCOPE_SYSTEM);
      LDPG(t + 1);  // prefetch next pg; overlaps the spin below
      if (tid < 64) {
        const unsigned tgt = (unsigned)(t + 1);
        while (true) {
          unsigned v = __hip_atomic_load(&arr[tid * FPAD], __ATOMIC_RELAXED,
                                         __HIP_MEMORY_SCOPE_SYSTEM);
          if (__all((int)(v >= tgt))) break;
          __builtin_amdgcn_s_sleep(1);
        }
      }
      __syncthreads();
    }
  }
#undef LDPG
}

// ---------------- launcher ----------------
static inline size_t align_up(size_t x, size_t a) { return (x + a - 1) & ~(a - 1); }

extern "C" void kernel_launch(void* const* d_in, const int* in_sizes, int n_in,
                              void* d_out, int out_size, void* d_ws, size_t ws_size,
                              hipStream_t stream) {
  const float* x    = (const float*)d_in[0];
  const float* c0   = (const float*)d_in[1];
  const float* h0   = (const float*)d_in[2];
  const float* W_ih = (const float*)d_in[3];
  const float* W_hh = (const float*)d_in[4];
  const float* b_ih = (const float*)d_in[5];
  const float* b_hh = (const float*)d_in[6];
  float* out = (float*)d_out;

  const size_t pg_elems = (size_t)TSEQ * NB * NG;
  const size_t xb_bytes = (size_t)TSEQ * NB * DI * 2;
  const size_t wt_bytes = (size_t)NG * 1024 * 2;
  const size_t hb_bytes = (size_t)2 * NB * DHID * 2;
  const size_t bsum_bytes = (size_t)NG * 4;
  const size_t arr_bytes = (size_t)NGRP * WPG * FPAD * 4;

  auto layout = [&](size_t pg_bytes, size_t* offs) {
    size_t o = 0;
    offs[0] = o; o = align_up(o + pg_bytes, 256);
    offs[1] = o; o = align_up(o + xb_bytes, 256);
    offs[2] = o; o = align_up(o + wt_bytes, 256);
    offs[3] = o; o = align_up(o + wt_bytes, 256);
    offs[4] = o; o = align_up(o + hb_bytes, 256);
    offs[5] = o; o = align_up(o + bsum_bytes, 256);
    offs[6] = o; o = align_up(o + arr_bytes, 256);
    return o;
  };
  size_t offs[7];
  size_t need_f32 = layout(pg_elems * 4, offs);
  bool pf32 = ws_size >= need_f32;
  if (!pf32) layout(pg_elems * 2, offs);

  char* ws = (char*)d_ws;
  void* pg = ws + offs[0];
  unsigned short* xb   = (unsigned short*)(ws + offs[1]);
  unsigned short* wihT = (unsigned short*)(ws + offs[2]);
  unsigned short* whhT = (unsigned short*)(ws + offs[3]);
  unsigned short* hbuf = (unsigned short*)(ws + offs[4]);
  float* bsum = (float*)(ws + offs[5]);
  unsigned* arrive = (unsigned*)(ws + offs[6]);

  k_convert_x<<<2048, 256, 0, stream>>>(x, xb, (int)((size_t)TSEQ * NB * DI / 4));
  k_transpose_w<<<dim3(NG / 32, 1024 / 32), 256, 0, stream>>>(W_ih, wihT);
  k_transpose_w<<<dim3(NG / 32, 1024 / 32), 256, 0, stream>>>(W_hh, whhT);
  k_init<<<(NB * DHID + 255) / 256, 256, 0, stream>>>(h0, b_ih, b_hh, hbuf, bsum, arrive);

  dim3 ggrid(TSEQ * NB / 128, NG / 128);
  if (pf32)
    k_gemm_pregates<true><<<ggrid, 256, 0, stream>>>(xb, wihT, pg);
  else
    k_gemm_pregates<false><<<ggrid, 256, 0, stream>>>(xb, wihT, pg);

  if (pf32)
    k_lstm<true><<<NWGS, 256, 0, stream>>>(whhT, pg, c0, bsum, hbuf, out, arrive);
  else
    k_lstm<false><<<NWGS, 256, 0, stream>>>(whhT, pg, c0, bsum, hbuf, out, arrive);
}